// Round 9
// baseline (204.015 us; speedup 1.0000x reference)
//
#include <hip/hip_runtime.h>

#define NBATCH 4096
#define SEQ 512
#define HID 5
#define NEMB 64

__device__ __forceinline__ float fexp2(float x){ return __builtin_amdgcn_exp2f(x); }
__device__ __forceinline__ float frcp(float x){ return __builtin_amdgcn_rcpf(x); }

// quad_perm broadcast of quad-lane j to the whole quad (full-rate VALU)
#define DPPQ(v, j) __int_as_float(__builtin_amdgcn_update_dpp(0, __float_as_int(v), ((j) * 0x55), 0xF, 0xF, true))
// readlane (constant lane) -> SGPR; merge per half with cndmask
#define RL(v, lane) __builtin_amdgcn_readlane(__float_as_int(v), (lane))

__global__ __launch_bounds__(64) void lstm_enc_kernel(
    const float* __restrict__ x_num, const int* __restrict__ x_cat,
    const float* __restrict__ embed, const float* __restrict__ W_ih,
    const float* __restrict__ W_hh, const float* __restrict__ b_ih,
    const float* __restrict__ b_hh, float* __restrict__ out)
{
    __shared__ float4 s_emb[NEMB];
    int tid = threadIdx.x;
    s_emb[tid] = ((const float4*)embed)[tid];
    __syncthreads();

    // 2 batch elements per wave, one per 32-lane half.
    // lane l in half: quad q=l>>2 holds unit k=min(q,4); g=l&3 is the gate.
    int halfi = tid >> 5;
    bool hs   = (tid >= 32);                // half selector for cndmask merge
    int l     = tid & 31;
    int b     = blockIdx.x * 2 + halfi;
    int k     = ((l >> 2) < HID) ? (l >> 2) : (HID - 1);
    int g     = l & 3;                      // 0:i 1:f 2:g 3:o
    bool st   = (l < 20) && (g == 0);       // h_k holder lanes: 0,4,8,12,16

    const float L2E = 1.4426950408889634f;
    float s_  = (g == 2) ? (-2.0f * L2E) : (-L2E);   // prescale (tanh gate: 2*sigma-1 form)
    float fm  = (g == 2) ? 2.0f : 1.0f;
    float fb  = (g == 2) ? -1.0f : 0.0f;

    int row = g * HID + k;
    float wi_[5], wh_[5];
#pragma unroll
    for (int d = 0; d < 5; ++d) {
        wi_[d] = W_ih[row * 5 + d] * s_;
        wh_[d] = W_hh[row * 5 + d] * s_;
    }
    float bias = (b_ih[row] + b_hh[row]) * s_;

    const float4* xp = (const float4*)(x_num + (size_t)b * SEQ);
    const int4*   cp = (const int4*)(x_cat + (size_t)b * SEQ);
    float* outp = out + (size_t)b * SEQ * HID + k;

    float h = 0.f, c = 0.f;
    float hb0 = 0.f, hb1 = 0.f, hb2 = 0.f, hb3 = 0.f, hb4 = 0.f;

    float4 xf = xp[0];
    int4   cf = cp[0];
    float4 ec_[4];
    ec_[0] = s_emb[cf.x]; ec_[1] = s_emb[cf.y];
    ec_[2] = s_emb[cf.z]; ec_[3] = s_emb[cf.w];

    for (int t0 = 0; t0 < SEQ; t0 += 4) {
        int nidx = (t0 + 4 < SEQ) ? ((t0 >> 2) + 1) : 0;
        float4 xf_n = xp[nidx];
        int4   cf_n = cp[nidx];

        float xn_a[4] = {xf.x, xf.y, xf.z, xf.w};

        // off-chain: bias + x + emb part (one gate value per lane)
        float xa[4];
#pragma unroll
        for (int u = 0; u < 4; ++u) {
            float4 e = ec_[u];
            float a = fmaf(xn_a[u], wi_[0], bias);
            a = fmaf(e.x, wi_[1], a);
            a = fmaf(e.y, wi_[2], a);
            a = fmaf(e.z, wi_[3], a);
            a = fmaf(e.w, wi_[4], a);
            xa[u] = a;
        }

#pragma unroll
        for (int u = 0; u < 4; ++u) {
            // h-part: 5-FMA dot with broadcast h (per-lane gate row)
            float a = xa[u];
            a = fmaf(hb0, wh_[0], a);
            a = fmaf(hb1, wh_[1], a);
            a = fmaf(hb2, wh_[2], a);
            a = fmaf(hb3, wh_[3], a);
            a = fmaf(hb4, wh_[4], a);

            // ONE sigma per lane; tanh-gate lanes apply 2r-1 via per-lane consts
            float r = frcp(1.0f + fexp2(a));
            float v = fmaf(r, fm, fb);

            // gather i,f,g,o within the unit's quad (full-rate DPP)
            float ai = DPPQ(v, 0);
            float af = DPPQ(v, 1);
            float ag = DPPQ(v, 2);
            float ao = DPPQ(v, 3);

            // c,h computed redundantly on all lanes of the quad
            c = fmaf(af, c, ai * ag);
            float tc = fmaf(frcp(1.0f + fexp2(c * (-2.0f * L2E))), 2.0f, -1.0f);
            h = ao * tc;

            // ---- VALU-only broadcast: readlane (const lanes) + per-half cndmask ----
            // h_k for half A at lane 4k, for half B at lane 32+4k (quads replicate h).
            hb0 = __int_as_float(hs ? RL(h, 32) : RL(h, 0));
            hb1 = __int_as_float(hs ? RL(h, 36) : RL(h, 4));
            hb2 = __int_as_float(hs ? RL(h, 40) : RL(h, 8));
            hb3 = __int_as_float(hs ? RL(h, 44) : RL(h, 12));
            hb4 = __int_as_float(hs ? RL(h, 48) : RL(h, 16));

            if (st) outp[(t0 + u) * HID] = h;
        }

        ec_[0] = s_emb[cf_n.x]; ec_[1] = s_emb[cf_n.y];
        ec_[2] = s_emb[cf_n.z]; ec_[3] = s_emb[cf_n.w];
        xf = xf_n;
    }

    if (st) {
        size_t base = (size_t)NBATCH * SEQ * HID;
        out[base + (size_t)b * HID + k] = h;                          // hT
        out[base + (size_t)NBATCH * HID + (size_t)b * HID + k] = c;   // cT
    }
}

extern "C" void kernel_launch(void* const* d_in, const int* in_sizes, int n_in,
                              void* d_out, int out_size, void* d_ws, size_t ws_size,
                              hipStream_t stream) {
    const float* x_num = (const float*)d_in[0];
    const int*   x_cat = (const int*)d_in[1];
    const float* embed = (const float*)d_in[2];
    const float* W_ih  = (const float*)d_in[3];
    const float* W_hh  = (const float*)d_in[4];
    const float* b_ih  = (const float*)d_in[5];
    const float* b_hh  = (const float*)d_in[6];
    float* out = (float*)d_out;

    dim3 grid(NBATCH / 2);   // 2048 blocks, 1 wave each -> 2 waves/SIMD
    dim3 block(64);
    hipLaunchKernelGGL(lstm_enc_kernel, grid, block, 0, stream,
                       x_num, x_cat, embed, W_ih, W_hh, b_ih, b_hh, out);
}

// Round 10
// 97.321 us; speedup vs baseline: 2.0963x; 2.0963x over previous
//
#include <hip/hip_runtime.h>

#define NBATCH 4096
#define SEQ 512
#define HID 5
#define NEMB 64

__device__ __forceinline__ float fexp2(float x){ return __builtin_amdgcn_exp2f(x); }
__device__ __forceinline__ float frcp(float x){ return __builtin_amdgcn_rcpf(x); }

// quad_perm broadcast of quad-lane j to the whole quad (bound_ctrl=1, clean)
#define DPPQ(v, j) __int_as_float(__builtin_amdgcn_update_dpp(0, __float_as_int(v), ((j) * 0x55), 0xF, 0xF, true))
// zero-fill DPP permute (bound_ctrl=1, no merge, no old-value dependency)
#define DPPZ(v, CTRL) __int_as_float(__builtin_amdgcn_update_dpp(0, __float_as_int(v), (CTRL), 0xF, 0xF, true))
// empirically pinned on this toolchain (r5/r7 passed): 0x104: lane i reads i+4 (0 if out of row)
// 0x114: i-4; 0x10C: i+12; 0x11C: i-12; 0x128 = row_ror:8 (direction-symmetric).
#define ROT4(v)  (DPPZ(v, 0x104) + DPPZ(v, 0x11C))   /* h[(i+4)  & 15] within row */
#define ROT8(v)  (DPPZ(v, 0x128))                    /* h[(i+8)  & 15] */
#define ROT12(v) (DPPZ(v, 0x10C) + DPPZ(v, 0x114))   /* h[(i+12) & 15] */

__global__ __launch_bounds__(64) void lstm_enc_kernel(
    const float* __restrict__ x_num, const int* __restrict__ x_cat,
    const float* __restrict__ embed, const float* __restrict__ W_ih,
    const float* __restrict__ W_hh, const float* __restrict__ b_ih,
    const float* __restrict__ b_hh, float* __restrict__ out)
{
    __shared__ float4 s_emb[NEMB];
    int tid = threadIdx.x;
    s_emb[tid] = ((const float4*)embed)[tid];
    __syncthreads();

    // element = 16-lane DPP row. lane l in row: quad q=l>>2 owns unit q (comp "O");
    // unit 4 is replicated on ALL lanes as a second scalar (comp "4"). gate g=l&3.
    int grp = tid >> 4;                 // 4 elements per wave
    int l   = tid & 15;
    int q   = l >> 2;
    int g   = l & 3;                    // 0:i 1:f 2:g 3:o
    int b   = blockIdx.x * 4 + grp;

    bool st  = (g == 0) || (l == 1);    // 5 storing lanes: q-holders (g==0) + lane1 for unit 4
    bool is4 = (l == 1);
    int  col = is4 ? 4 : q;

    const float L2E = 1.4426950408889634f;
    const float CS  = -2.0f * L2E;
    float s_  = (g == 2) ? CS : -L2E;   // prescale: tanh gate -2log2e, sigmoid -log2e
    float fm  = (g == 2) ? 2.0f : 1.0f; // activation fixup v = r*fm+fb
    float fb  = (g == 2) ? -1.0f : 0.0f;

    int rowO = g * HID + q;             // own-unit gate row
    int row4 = g * HID + 4;             // unit-4 gate row
    float wiO[5], wi4[5], wrO[5], wr4[5];
#pragma unroll
    for (int d = 0; d < 5; ++d) {
        wiO[d] = W_ih[rowO * 5 + d] * s_;
        wi4[d] = W_ih[row4 * 5 + d] * s_;
    }
#pragma unroll
    for (int r = 0; r < 4; ++r) {       // weights pre-permuted for rotate-dot
        int idx = (q + r) & 3;
        wrO[r] = W_hh[rowO * 5 + idx] * s_;
        wr4[r] = W_hh[row4 * 5 + idx] * s_;
    }
    wrO[4] = W_hh[rowO * 5 + 4] * s_;
    wr4[4] = W_hh[row4 * 5 + 4] * s_;
    float biasO = (b_ih[rowO] + b_hh[rowO]) * s_;
    float bias4 = (b_ih[row4] + b_hh[row4]) * s_;

    const float4* xp = (const float4*)(x_num + (size_t)b * SEQ);
    const int4*   cp = (const int4*)(x_cat + (size_t)b * SEQ);
    float* outp = out + (size_t)b * SEQ * HID;

    float hq = 0.f, cq = 0.f, h4 = 0.f, c4 = 0.f;

    // depth-2 prefetch of x/cat; 1-block-ahead emb
    float4 xf_c = xp[0];            int4 cf_c = cp[0];
    float4 xf_1 = xp[1];            int4 cf_1 = cp[1];
    float4 ec_c[4];
    ec_c[0] = s_emb[cf_c.x]; ec_c[1] = s_emb[cf_c.y];
    ec_c[2] = s_emb[cf_c.z]; ec_c[3] = s_emb[cf_c.w];

    for (int t0 = 0; t0 < SEQ; t0 += 4) {
        int n2 = (t0 >> 2) + 2;
        if (n2 > (SEQ / 4 - 1)) n2 = SEQ / 4 - 1;
        float4 xf_2 = xp[n2];
        int4   cf_2 = cp[n2];

        // next block's emb rows (cf_1 loaded 1-2 blocks ago; consumed next block)
        float4 ec_n0 = s_emb[cf_1.x];
        float4 ec_n1 = s_emb[cf_1.y];
        float4 ec_n2 = s_emb[cf_1.z];
        float4 ec_n3 = s_emb[cf_1.w];

        float xn_a[4] = {xf_c.x, xf_c.y, xf_c.z, xf_c.w};

        // off-chain: bias + x + emb for both components, 4 steps
        float xaO[4], xa4[4];
#pragma unroll
        for (int u = 0; u < 4; ++u) {
            float4 e = ec_c[u];
            float aO = fmaf(xn_a[u], wiO[0], biasO);
            float a4v = fmaf(xn_a[u], wi4[0], bias4);
            aO  = fmaf(e.x, wiO[1], aO);   a4v = fmaf(e.x, wi4[1], a4v);
            aO  = fmaf(e.y, wiO[2], aO);   a4v = fmaf(e.y, wi4[2], a4v);
            aO  = fmaf(e.z, wiO[3], aO);   a4v = fmaf(e.z, wi4[3], a4v);
            aO  = fmaf(e.w, wiO[4], aO);   a4v = fmaf(e.w, wi4[4], a4v);
            xaO[u] = aO; xa4[u] = a4v;
        }

#pragma unroll
        for (int u = 0; u < 4; ++u) {
            // rotate-dot: local terms first (h4, own h_q), then row-rotations
            float aO = xaO[u], a4v = xa4[u];
            aO = fmaf(h4, wrO[4], aO);   a4v = fmaf(h4, wr4[4], a4v);
            aO = fmaf(hq, wrO[0], aO);   a4v = fmaf(hq, wr4[0], a4v);
            float t4  = ROT4(hq);
            float t8  = ROT8(hq);
            float t12 = ROT12(hq);
            aO = fmaf(t4,  wrO[1], aO);  a4v = fmaf(t4,  wr4[1], a4v);
            aO = fmaf(t8,  wrO[2], aO);  a4v = fmaf(t8,  wr4[2], a4v);
            aO = fmaf(t12, wrO[3], aO);  a4v = fmaf(t12, wr4[3], a4v);

            // one sigma per component; tanh-gate lanes fix up 2r-1
            float rO = frcp(1.0f + fexp2(aO));
            float r4 = frcp(1.0f + fexp2(a4v));
            float vO = fmaf(rO, fm, fb);
            float v4 = fmaf(r4, fm, fb);

            // gather i,f,g,o within the quad for both components
            float aiO = DPPQ(vO, 0), afO = DPPQ(vO, 1), agO = DPPQ(vO, 2), aoO = DPPQ(vO, 3);
            float ai4 = DPPQ(v4, 0), af4 = DPPQ(v4, 1), ag4 = DPPQ(v4, 2), ao4 = DPPQ(v4, 3);

            cq = fmaf(afO, cq, aiO * agO);
            c4 = fmaf(af4, c4, ai4 * ag4);

            float tO = frcp(1.0f + fexp2(cq * CS));
            float t4c = frcp(1.0f + fexp2(c4 * CS));
            hq = fmaf(tO,  aoO + aoO, -aoO);   // o * (2*sigma(2c)-1)
            h4 = fmaf(t4c, ao4 + ao4, -ao4);

            if (st) outp[(t0 + u) * HID + col] = is4 ? h4 : hq;
        }

        ec_c[0] = ec_n0; ec_c[1] = ec_n1; ec_c[2] = ec_n2; ec_c[3] = ec_n3;
        xf_c = xf_1; xf_1 = xf_2;
        cf_c = cf_1; cf_1 = cf_2;
    }

    if (st) {
        size_t base = (size_t)NBATCH * SEQ * HID;
        out[base + (size_t)b * HID + col] = is4 ? h4 : hq;                          // hT
        out[base + (size_t)NBATCH * HID + (size_t)b * HID + col] = is4 ? c4 : cq;   // cT
    }
}

extern "C" void kernel_launch(void* const* d_in, const int* in_sizes, int n_in,
                              void* d_out, int out_size, void* d_ws, size_t ws_size,
                              hipStream_t stream) {
    const float* x_num = (const float*)d_in[0];
    const int*   x_cat = (const int*)d_in[1];
    const float* embed = (const float*)d_in[2];
    const float* W_ih  = (const float*)d_in[3];
    const float* W_hh  = (const float*)d_in[4];
    const float* b_ih  = (const float*)d_in[5];
    const float* b_hh  = (const float*)d_in[6];
    float* out = (float*)d_out;

    dim3 grid(NBATCH / 4);   // 1024 blocks, 1 wave each: 4 elements/wave, 1 wave/SIMD
    dim3 block(64);
    hipLaunchKernelGGL(lstm_enc_kernel, grid, block, 0, stream,
                       x_num, x_cat, embed, W_ih, W_hh, b_ih, b_hh, out);
}

// Round 11
// 89.955 us; speedup vs baseline: 2.2680x; 1.0819x over previous
//
#include <hip/hip_runtime.h>

#define NBATCH 4096
#define SEQ 512
#define HID 5
#define NEMB 64

__device__ __forceinline__ float fexp2(float x){ return __builtin_amdgcn_exp2f(x); }
__device__ __forceinline__ float frcp(float x){ return __builtin_amdgcn_rcpf(x); }

// ds_swizzle BitMode: new_lane = (lane&0)|4k -> all lanes of each 32-half read lane 4k
#define SWZ(v, k) __int_as_float(__builtin_amdgcn_ds_swizzle(__float_as_int(v), ((4*(k)) << 5)))
// quad_perm broadcast of quad-lane j to the whole quad
#define DPPQ(v, j) __int_as_float(__builtin_amdgcn_update_dpp(0, __float_as_int(v), ((j) * 0x55), 0xF, 0xF, true))

__global__ __launch_bounds__(64) void lstm_enc_kernel(
    const float* __restrict__ x_num, const int* __restrict__ x_cat,
    const float* __restrict__ embed, const float* __restrict__ W_ih,
    const float* __restrict__ W_hh, const float* __restrict__ b_ih,
    const float* __restrict__ b_hh, float* __restrict__ out)
{
    __shared__ float4 s_emb[NEMB];
    int tid = threadIdx.x;
    s_emb[tid] = ((const float4*)embed)[tid];
    __syncthreads();

    // 2 batch elements per wave, one per 32-lane half (r6 layout).
    // lane l in half: quad q=l>>2 owns unit k=min(q,4); g=l&3 is the gate.
    int halfi = tid >> 5;
    int l     = tid & 31;
    int b     = blockIdx.x * 2 + halfi;
    int k     = ((l >> 2) < HID) ? (l >> 2) : (HID - 1);
    int g     = l & 3;                      // 0:i 1:f 2:g 3:o
    bool st   = (l < 20) && (g == 0);       // h_k holder lanes: 0,4,8,12,16

    const float L2E = 1.4426950408889634f;
    const float CS  = -2.0f * L2E;
    float s_  = (g == 2) ? CS : (-L2E);     // prescale (tanh gate: 2*sigma-1 form)
    float fm  = (g == 2) ? 2.0f : 1.0f;
    float fb  = (g == 2) ? -1.0f : 0.0f;

    int row = g * HID + k;
    float wi_[5], whz[5];
#pragma unroll
    for (int d = 0; d < 5; ++d) {
        wi_[d] = W_ih[row * 5 + d] * s_;
        whz[d] = W_hh[row * 5 + d] * s_;
    }
    float wh_own = whz[k];                  // own-unit h weight (h is local post-DPPQ)
    whz[k] = 0.0f;                          // zero own index in broadcast weights

    const float4* xp = (const float4*)(x_num + (size_t)b * SEQ);
    const int4*   cp = (const int4*)(x_cat + (size_t)b * SEQ);
    float* outp = out + (size_t)b * SEQ * HID + k;
    float bias = (b_ih[row] + b_hh[row]) * s_;

    float h = 0.f, c = 0.f;
    float hb0 = 0.f, hb1 = 0.f, hb2 = 0.f, hb3 = 0.f, hb4 = 0.f;

    // depth-2 prefetch of x/cat; emb staged one block ahead
    float4 xf_c = xp[0];  int4 cf_c = cp[0];
    float4 xf_1 = xp[1];  int4 cf_1 = cp[1];
    float4 ec_c[4];
    ec_c[0] = s_emb[cf_c.x]; ec_c[1] = s_emb[cf_c.y];
    ec_c[2] = s_emb[cf_c.z]; ec_c[3] = s_emb[cf_c.w];

    // prologue: xa for t=0
    float xa_cur;
    {
        float4 e = ec_c[0];
        float a = fmaf(xf_c.x, wi_[0], bias);
        a = fmaf(e.x, wi_[1], a);
        a = fmaf(e.y, wi_[2], a);
        a = fmaf(e.z, wi_[3], a);
        a = fmaf(e.w, wi_[4], a);
        xa_cur = a;
    }

    for (int t0 = 0; t0 < SEQ; t0 += 4) {
        int n2 = (t0 >> 2) + 2;
        if (n2 > (SEQ / 4 - 1)) n2 = SEQ / 4 - 1;
        float4 xf_2 = xp[n2];
        int4   cf_2 = cp[n2];

        // next block's emb rows (cf_1 is a full block old -> long-landed)
        float4 ec_n0 = s_emb[cf_1.x];
        float4 ec_n1 = s_emb[cf_1.y];
        float4 ec_n2 = s_emb[cf_1.z];
        float4 ec_n3 = s_emb[cf_1.w];

        float xn_a[4] = {xf_c.x, xf_c.y, xf_c.z, xf_c.w};

#pragma unroll
        for (int u = 0; u < 4; ++u) {
            // ---- recurrent chain ----
            // local term first (own h available without swizzle), then broadcasts
            float a = fmaf(h, wh_own, xa_cur);
            a = fmaf(hb0, whz[0], a);
            a = fmaf(hb1, whz[1], a);
            a = fmaf(hb2, whz[2], a);
            a = fmaf(hb3, whz[3], a);
            a = fmaf(hb4, whz[4], a);

            float r = frcp(1.0f + fexp2(a));
            float v = fmaf(r, fm, fb);

            float ai = DPPQ(v, 0);
            float af = DPPQ(v, 1);
            float ag = DPPQ(v, 2);
            float ao = DPPQ(v, 3);

            c = fmaf(af, c, ai * ag);
            float tc = fmaf(frcp(1.0f + fexp2(c * CS)), 2.0f, -1.0f);
            float hn = ao * tc;

            // issue next-step broadcasts IMMEDIATELY
            hb0 = SWZ(hn, 0);
            hb1 = SWZ(hn, 1);
            hb2 = SWZ(hn, 2);
            hb3 = SWZ(hn, 3);
            hb4 = SWZ(hn, 4);

            // ---- fill window: xa for step t+1 + store (independent of swizzles) ----
            {
                float xn_nxt = (u < 3) ? xn_a[u + 1] : xf_1.x;
                float4 e     = (u < 3) ? ec_c[u + 1] : ec_n0;
                float an = fmaf(xn_nxt, wi_[0], bias);
                an = fmaf(e.x, wi_[1], an);
                an = fmaf(e.y, wi_[2], an);
                an = fmaf(e.z, wi_[3], an);
                an = fmaf(e.w, wi_[4], an);
                xa_cur = an;
            }
            if (st) outp[(t0 + u) * HID] = hn;

            h = hn;
        }

        ec_c[0] = ec_n0; ec_c[1] = ec_n1; ec_c[2] = ec_n2; ec_c[3] = ec_n3;
        xf_c = xf_1; xf_1 = xf_2;
        cf_c = cf_1; cf_1 = cf_2;
    }

    if (st) {
        size_t base = (size_t)NBATCH * SEQ * HID;
        out[base + (size_t)b * HID + k] = h;                          // hT
        out[base + (size_t)NBATCH * HID + (size_t)b * HID + k] = c;   // cT
    }
}

extern "C" void kernel_launch(void* const* d_in, const int* in_sizes, int n_in,
                              void* d_out, int out_size, void* d_ws, size_t ws_size,
                              hipStream_t stream) {
    const float* x_num = (const float*)d_in[0];
    const int*   x_cat = (const int*)d_in[1];
    const float* embed = (const float*)d_in[2];
    const float* W_ih  = (const float*)d_in[3];
    const float* W_hh  = (const float*)d_in[4];
    const float* b_ih  = (const float*)d_in[5];
    const float* b_hh  = (const float*)d_in[6];
    float* out = (float*)d_out;

    dim3 grid(NBATCH / 2);   // 2048 blocks, 1 wave each -> 2 waves/SIMD
    dim3 block(64);
    hipLaunchKernelGGL(lstm_enc_kernel, grid, block, 0, stream,
                       x_num, x_cat, embed, W_ih, W_hh, b_ih, b_hh, out);
}